// Round 9
// baseline (161.044 us; speedup 1.0000x reference)
//
#include <hip/hip_runtime.h>
#include <hip/hip_bf16.h>

// ---------------------------------------------------------------------------
// InferCellV2 R14: R12 champion + relu-pad folded into conv<1> staging.
// R13b result: moving B from LDS to L1/regs was neutral (154 vs 149) - LDS
// byte reduction is offset 1:1 by L1 cost; conv core is at its fragment-
// traffic floor for 64x64 wave tiles. fp8 ruled out numerically (6% rel err
// x output std ~20-40 > absmax tol 2.0). Remaining controllable cost: the
// pre_kernel relu-pad pass (33.5MB r + 16.8MB w ~= 8-10us) + conv<1>'s 19MB
// re-read of r0. R14: conv<1> reg-stages its A-tile straight from raw fp32
// NCHW input (relu + cvt + swizzle in-reg, halo zeroed in-reg), ds_write to
// LDS AND writes the padded swizzled tile back to r0 (coalesced 16B/thread)
// for conv<2>/<3>'s unchanged gld16 path. Strip-overlap rows double-written
// with identical values (benign). pre shrinks to weights + r1/r2 halo.
// Base structure (R12, verified): A+B LDS, barrier-free 9-tap source loop,
// 1-deep fragment register pipeline fA/fB[2][4] (static idx), oc-permuted
// wt (acc col n*16+l15 = true oc l15*4+n -> 8B-contiguous node epilogue),
// __launch_bounds__(512,1), grid 256 = 1 block/CU.
// Layouts (verified conflict-free R3/R6):
//   activations: zero-padded NHWC bf16 [B][34][34][64], chunk cb of pixel p
//     at p*128 + ((cb^(p&7))*16); weights wt[l][tap][o_s][i], chunk i>>3 of
//     row o_s at slot (i>>3)^(o_s&7). Staging = linear 16B chunks.
// Wave tile 64px x 64oc = 4x4 MFMA 16x16x32, 64 acc + 64 frag VGPRs.
// ---------------------------------------------------------------------------

typedef __bf16 bf16x8 __attribute__((ext_vector_type(8)));
typedef float floatx4 __attribute__((ext_vector_type(4)));
typedef unsigned int uint32;

#define PADW 34
#define PIMG (PADW * PADW)
#define ROWB (PADW * 64 * 2)        // 4352 B per padded NHWC row
#define A_LDS (18 * ROWB)           // 78336 (16 out rows + 2 halo)
#define A_CHUNKS (A_LDS / 16)       // 4896 = 9*512 + 288
#define A_TAIL (A_CHUNKS - 9 * 512) // 288
#define TAPB (64 * 64 * 2)          // 8192 B per weight tap
#define B_LDS (9 * TAPB)            // 73728
#define SMEM_BYTES (A_LDS + B_LDS)  // 152064 -> 1 block/CU

__device__ __forceinline__ void gld16(const char* g, char* l) {
    __builtin_amdgcn_global_load_lds(
        (const __attribute__((address_space(1))) uint32*)g,
        (__attribute__((address_space(3))) uint32*)l, 16, 0, 0);
}

// ---------------- pre-pass: prep_weights + zero_halo (r1,r2 only) ----------
__global__ __launch_bounds__(256) void pre_kernel(
    const float* __restrict__ a1, const float* __restrict__ a2,
    const float* __restrict__ W, __hip_bfloat16* __restrict__ wt,
    __hip_bfloat16* __restrict__ r1, __hip_bfloat16* __restrict__ r2) {
    int blk = blockIdx.x;
    int tid = threadIdx.x;

    if (blk < 864) {                 // ---- weights: fold scale + oc-permute
        int idx = blk * 256 + tid;   // 6*9*64*64 = 221184 exact
        int i = idx & 63;
        int o = (idx >> 6) & 63;     // TRUE oc
        int rest = idx >> 12;
        int t = rest % 9;
        int l = rest / 9;
        int ji = i >> 3, jo = o >> 3;
        float ain = 0.f, aout = 0.f;
#pragma unroll
        for (int j = 0; j < 8; ++j) {
            ain  += (j >= ji) ? a1[j] : 0.f;
            aout += (j >= jo) ? a2[j] : 0.f;
        }
        float v = W[(size_t)((l * 64 + o) * 64 + i) * 9 + t] * ain * aout;
        // storage col o_s: acc col c = n*16+l15 then holds true oc l15*4+n
        int os = ((o & 3) << 4) + (o >> 2);
        size_t e = (size_t)(l * 9 + t) * 4096 + os * 64 +
                   ((((i >> 3) ^ (os & 7)) << 3) + (i & 7));
        wt[e] = __float2bfloat16(v);
    } else {                         // ---- zero halo ring, image b (r1, r2)
        int b = blk - 864;           // r0 halo written by conv<1> writeback
        __hip_bfloat16* bufs[2] = {r1, r2};
#pragma unroll
        for (int f = 0; f < 2; ++f) {
            uint32* buf = (uint32*)(bufs[f] + (size_t)b * PIMG * 64);
            for (int idx = tid; idx < 132 * 32; idx += 256) {
                int slot = idx >> 5, u = idx & 31;
                int yy, xx;
                if (slot < 34)      { yy = 0;  xx = slot; }
                else if (slot < 68) { yy = 33; xx = slot - 34; }
                else { int s2 = slot - 68; yy = 1 + (s2 >> 1); xx = (s2 & 1) * 33; }
                buf[(size_t)(yy * PADW + xx) * 32 + u] = 0u;
            }
        }
    }
}

// ---------------- conv stage: pipelined free-run within each source ---------
// Block: image b = blk>>1, strip y0 = (blk&1)*16. Wave wv: rows y0+2wv,+1.
// A-frag: l15 = px, quad*8+q*32 = in-ch. B-frag: l15 = storage col (true oc
// = l15*4+n). C/D: M(pixel) = quad*4+r.
// RAW: source 0 is raw fp32 NCHW input; stage = relu+cvt+swizzle in-reg,
// ds_write to LDS + coalesced writeback of the padded tile to r0wb.
template <int NSRC, bool FINAL, bool RAW>
__global__ __launch_bounds__(512, 1) void conv_stage(
    const __hip_bfloat16* __restrict__ s0,
    const __hip_bfloat16* __restrict__ s1,
    const __hip_bfloat16* __restrict__ s2,
    const __hip_bfloat16* __restrict__ wt,
    void* __restrict__ dstv, int l0,
    const float* __restrict__ rawin, __hip_bfloat16* __restrict__ r0wb) {
    extern __shared__ char smem[];               // A_LDS + B_LDS = 152064 B
    char* smemB = smem + A_LDS;
    int tid = threadIdx.x;
    int wv = tid >> 6, lane = tid & 63;
    int quad = lane >> 4, l15 = lane & 15;
    int blk = blockIdx.x;
    int b = blk >> 1, y0 = (blk & 1) << 4;

    const char* srcs[3] = {(const char*)s0, (const char*)s1, (const char*)s2};
    const char* gW = (const char*)wt + (size_t)l0 * 9 * (size_t)TAPB;
    const size_t aOff = (size_t)(b * PADW + y0) * PADW * 128;

    auto stage_A = [&](int s) {      // 18 padded rows, linear 16B DMA copy
        const char* gA = srcs[s] + aOff;
#pragma unroll
        for (int it = 0; it < 10; ++it) {
            int c = it * 512 + tid;
            if (it < 9 || tid < A_TAIL)
                gld16(gA + (size_t)c * 16, smem + (it * 512 + wv * 64) * 16);
        }
    };
    auto stage_B = [&](int s) {      // 9 taps of src s, linear 16B DMA copy
        const char* gB = gW + (size_t)s * 9 * TAPB;
#pragma unroll
        for (int it = 0; it < 9; ++it) {
            int c = it * 512 + tid;
            gld16(gB + (size_t)c * 16, smemB + (it * 512 + wv * 64) * 16);
        }
    };
    // RAW staging: chunk c = (R*34+px)*8 + sw; content = ic chunk
    // cb = sw ^ (P&7) of padded pixel P (zero outside image), relu'd.
    auto stage_raw = [&]() {
#pragma unroll
        for (int it = 0; it < 10; ++it) {
            int c = it * 512 + tid;
            if (it < 9 || tid < A_TAIL) {
                int sw = c & 7;
                int pix = c >> 3;                 // R*34 + px, 0..611
                int R = pix / 34, px = pix - R * 34;
                int P = (b * PADW + y0 + R) * PADW + px;
                int cb = sw ^ (P & 7);
                int y = y0 + R - 1, x = px - 1;   // image coords
                alignas(16) __hip_bfloat16 hv[8];
                if ((unsigned)y < 32u && (unsigned)x < 32u) {
                    const float* ip = rawin +
                        (((size_t)b * 64 + cb * 8) * 32 + y) * 32 + x;
#pragma unroll
                    for (int k = 0; k < 8; ++k)
                        hv[k] = __float2bfloat16(
                            fmaxf(ip[(size_t)k * 1024], 0.f));
                } else {
#pragma unroll
                    for (int k = 0; k < 8; ++k)
                        hv[k] = __float2bfloat16(0.f);
                }
                *(uint4*)(smem + (size_t)c * 16) = *(const uint4*)hv;
                *(uint4*)((char*)r0wb + aOff + (size_t)c * 16) =
                    *(const uint4*)hv;            // padded tile -> r0
            }
        }
    };

    // fragment loaders (step = (tap, q)); indices compile-time under unroll.
    auto ldA = [&](int tl, int q, bf16x8 (&dst)[4]) {
        const int ky = tl / 3, kx = tl % 3;
#pragma unroll
        for (int m = 0; m < 4; ++m) {
            int arow = 2 * wv + (m >> 1) + ky;      // LDS row 0..17
            int apx  = ((m & 1) << 4) + l15 + kx;   // 0..33
            int R = b * PADW + y0 + arow;           // global padded row
            int slot = ((q << 2) + quad) ^ ((2 * R + apx) & 7);
            dst[m] = *(const bf16x8*)(smem + arow * ROWB + apx * 128 +
                                      slot * 16);
        }
    };
    auto ldB = [&](int tl, int q, bf16x8 (&dst)[4]) {
#pragma unroll
        for (int n = 0; n < 4; ++n) {
            int o = (n << 4) + l15;                 // storage col
            int slot = ((q << 2) + quad) ^ (l15 & 7);
            dst[n] = *(const bf16x8*)(smemB + tl * TAPB + o * 128 +
                                      slot * 16);
        }
    };

    floatx4 acc[4][4];
#pragma unroll
    for (int m = 0; m < 4; ++m)
#pragma unroll
        for (int n = 0; n < 4; ++n) acc[m][n] = (floatx4){0.f, 0.f, 0.f, 0.f};

    if constexpr (RAW) stage_raw(); else stage_A(0);
    stage_B(0);
    __syncthreads();                 // src0 operands resident (ds+vm drained)

#pragma unroll 1
    for (int s = 0; s < NSRC; ++s) {
        // ---- 18-step (tap x q) loop, 1-deep register pipeline ----
        bf16x8 fA[2][4], fB[2][4];
        ldA(0, 0, fA[0]);
        ldB(0, 0, fB[0]);
#pragma unroll
        for (int st = 0; st < 18; ++st) {
            const int pb = st & 1;               // compile-time under unroll
            if (st < 17) {                       // load step st+1 into pb^1
                const int nt = (st + 1) >> 1, nq = (st + 1) & 1;
                ldA(nt, nq, fA[pb ^ 1]);
                ldB(nt, nq, fB[pb ^ 1]);
            }
            __builtin_amdgcn_s_setprio(1);
#pragma unroll
            for (int m = 0; m < 4; ++m)
#pragma unroll
                for (int n = 0; n < 4; ++n)
                    acc[m][n] = __builtin_amdgcn_mfma_f32_16x16x32_bf16(
                        fA[pb][m], fB[pb][n], acc[m][n], 0, 0, 0);
            __builtin_amdgcn_s_setprio(0);
        }
        if (s + 1 < NSRC) {          // source switch (R6 semantics)
            __syncthreads();         // all waves done reading src s operands
            stage_A(s + 1);
            stage_B(s + 1);
            __syncthreads();         // staging drained (vmcnt0 via barrier)
        }
    }

    // Epilogue. M(pixel)=quad*4+r (+16 odd m-tile); acc col c=n*16+l15 holds
    // TRUE oc l15*4+n (wt oc-permuted) -> lane's 4 n-values are contiguous.
    if (FINAL) {
        float* out = (float*)dstv;   // fp32 NCHW [128][64][32][32]
#pragma unroll
        for (int m = 0; m < 4; ++m) {
            int row = y0 + 2 * wv + (m >> 1);
#pragma unroll
            for (int n = 0; n < 4; ++n) {
                int o = (l15 << 2) + n;                     // TRUE oc
                *(floatx4*)(out + (((size_t)b * 64 + o) * 32 + row) * 32 +
                            ((m & 1) << 4) + (quad << 2)) = acc[m][n];
            }
        }
    } else {
        __hip_bfloat16* out = (__hip_bfloat16*)dstv;  // relu -> swizzled NHWC
#pragma unroll
        for (int m = 0; m < 4; ++m) {
            int row = y0 + 2 * wv + (m >> 1);
#pragma unroll
            for (int r = 0; r < 4; ++r) {
                int x = ((m & 1) << 4) + (quad << 2) + r;
                int p = (b * PADW + row + 1) * PADW + x + 1;
                alignas(8) __hip_bfloat16 hv[4];
#pragma unroll
                for (int n = 0; n < 4; ++n)
                    hv[n] = __float2bfloat16(fmaxf(acc[m][n][r], 0.f));
                // true chs l15*4..+3 = storage chunk l15>>1, half (l15&1)
                char* d8 = (char*)out + (size_t)p * 128 +
                           ((((l15 >> 1) ^ (p & 7)) << 4) + ((l15 & 1) << 3));
                *(uint2*)d8 = *(const uint2*)hv;
            }
        }
    }
}

// ---------------------------------------------------------------------------
extern "C" void kernel_launch(void* const* d_in, const int* in_sizes, int n_in,
                              void* d_out, int out_size, void* d_ws,
                              size_t ws_size, hipStream_t stream) {
    const float* inputs  = (const float*)d_in[0];
    const float* alphas1 = (const float*)d_in[1];
    const float* alphas2 = (const float*)d_in[2];
    const float* W       = (const float*)d_in[3];
    char* ws = (char*)d_ws;

    __hip_bfloat16* wt = (__hip_bfloat16*)(ws);                     // 442 KB
    __hip_bfloat16* r0 = (__hip_bfloat16*)(ws + ((size_t)1 << 20)); // 18.9 MB
    __hip_bfloat16* r1 = (__hip_bfloat16*)(ws + ((size_t)20 << 20));
    __hip_bfloat16* r2 = (__hip_bfloat16*)(ws + ((size_t)40 << 20));
    float* out = (float*)d_out;

    // Opt-in to >64KB dynamic LDS (idempotent; harmless under graph capture).
    (void)hipFuncSetAttribute((const void*)conv_stage<1, false, true>,
                              hipFuncAttributeMaxDynamicSharedMemorySize,
                              SMEM_BYTES);
    (void)hipFuncSetAttribute((const void*)conv_stage<2, false, false>,
                              hipFuncAttributeMaxDynamicSharedMemorySize,
                              SMEM_BYTES);
    (void)hipFuncSetAttribute((const void*)conv_stage<3, true, false>,
                              hipFuncAttributeMaxDynamicSharedMemorySize,
                              SMEM_BYTES);

    pre_kernel<<<864 + 128, 256, 0, stream>>>(alphas1, alphas2, W, wt,
                                              r1, r2);
    conv_stage<1, false, true><<<256, 512, SMEM_BYTES, stream>>>(
        r0, r1, r2, wt, (void*)r1, 0, inputs, r0);
    conv_stage<2, false, false><<<256, 512, SMEM_BYTES, stream>>>(
        r0, r1, r2, wt, (void*)r2, 1, nullptr, nullptr);
    conv_stage<3, true, false><<<256, 512, SMEM_BYTES, stream>>>(
        r0, r1, r2, wt, (void*)out, 3, nullptr, nullptr);
}